// Round 1
// baseline (50.558 us; speedup 1.0000x reference)
//
#include <hip/hip_runtime.h>

// Haar wavedec, LEVEL=5, on x:(64,64,8192) f32.
// Output per row (L=8192): [cA5(256) | cD5(256) | cD4(512) | cD3(1024) | cD2(2048) | cD1(4096)]
// Since 2^5 = 32, a thread owning 32 consecutive input elements computes the
// full cascade locally: thread t of a row -> cA5[t], cD5[t], cD4[2t..], cD3[4t..],
// cD2[8t..], cD1[16t..]. No LDS, no syncthreads.

#define INV_SQRT2 0.70710678118654752440f

__global__ void __launch_bounds__(256)
haar5_kernel(const float* __restrict__ x, float* __restrict__ out) {
    const long long row = blockIdx.x;        // 0 .. 4095  (64*64 rows)
    const int t = threadIdx.x;               // 0 .. 255   (8192/32 chunks)

    const float* __restrict__ xr = x + row * 8192LL;
    float* __restrict__ orow = out + row * 8192LL;

    // Load 32 consecutive floats (128 B) as 8x float4. 16B-aligned.
    float v[32];
    const float4* __restrict__ src = reinterpret_cast<const float4*>(xr + t * 32);
#pragma unroll
    for (int j = 0; j < 8; ++j) {
        float4 f = src[j];
        v[4 * j + 0] = f.x; v[4 * j + 1] = f.y;
        v[4 * j + 2] = f.z; v[4 * j + 3] = f.w;
    }

    // Level 1: 32 -> 16
    float d1[16], a1[16];
#pragma unroll
    for (int k = 0; k < 16; ++k) {
        d1[k] = (v[2 * k] - v[2 * k + 1]) * INV_SQRT2;
        a1[k] = (v[2 * k] + v[2 * k + 1]) * INV_SQRT2;
    }
    // Level 2: 16 -> 8
    float d2[8], a2[8];
#pragma unroll
    for (int k = 0; k < 8; ++k) {
        d2[k] = (a1[2 * k] - a1[2 * k + 1]) * INV_SQRT2;
        a2[k] = (a1[2 * k] + a1[2 * k + 1]) * INV_SQRT2;
    }
    // Level 3: 8 -> 4
    float d3[4], a3[4];
#pragma unroll
    for (int k = 0; k < 4; ++k) {
        d3[k] = (a2[2 * k] - a2[2 * k + 1]) * INV_SQRT2;
        a3[k] = (a2[2 * k] + a2[2 * k + 1]) * INV_SQRT2;
    }
    // Level 4: 4 -> 2
    float d4[2], a4[2];
#pragma unroll
    for (int k = 0; k < 2; ++k) {
        d4[k] = (a3[2 * k] - a3[2 * k + 1]) * INV_SQRT2;
        a4[k] = (a3[2 * k] + a3[2 * k + 1]) * INV_SQRT2;
    }
    // Level 5: 2 -> 1
    float d5 = (a4[0] - a4[1]) * INV_SQRT2;
    float a5 = (a4[0] + a4[1]) * INV_SQRT2;

    // Stores — all segments contiguous per-thread, coalesced across threads.
    orow[t]       = a5;                                   // cA5
    orow[256 + t] = d5;                                   // cD5
    reinterpret_cast<float2*>(orow + 512)[t]  = make_float2(d4[0], d4[1]);          // cD4
    reinterpret_cast<float4*>(orow + 1024)[t] = make_float4(d3[0], d3[1], d3[2], d3[3]); // cD3
    float4* __restrict__ o2 = reinterpret_cast<float4*>(orow + 2048) + t * 2;       // cD2
    o2[0] = make_float4(d2[0], d2[1], d2[2], d2[3]);
    o2[1] = make_float4(d2[4], d2[5], d2[6], d2[7]);
    float4* __restrict__ o1 = reinterpret_cast<float4*>(orow + 4096) + t * 4;       // cD1
#pragma unroll
    for (int j = 0; j < 4; ++j)
        o1[j] = make_float4(d1[4 * j], d1[4 * j + 1], d1[4 * j + 2], d1[4 * j + 3]);
}

extern "C" void kernel_launch(void* const* d_in, const int* in_sizes, int n_in,
                              void* d_out, int out_size, void* d_ws, size_t ws_size,
                              hipStream_t stream) {
    const float* x = (const float*)d_in[0];
    float* out = (float*)d_out;
    // 64*64 = 4096 rows, one block per row, 256 threads x 32 elems = 8192.
    haar5_kernel<<<4096, 256, 0, stream>>>(x, out);
}

// Round 3
// 43.278 us; speedup vs baseline: 1.1682x; 1.1682x over previous
//
#include <hip/hip_runtime.h>

// Haar wavedec, LEVEL=5, x:(64,64,8192) f32.
// Output per row: [cA5(256) | cD5(256) | cD4(512) | cD3(1024) | cD2(2048) | cD1(4096)]
//
// Each lane owns 8 CONSECUTIVE input floats (2x float4 at 32B lane-stride ->
// line-complete coalesced load pairs). Levels 1-3 in registers; levels 4-5 via
// __shfl_xor(1)/__shfl_xor(2). cD1/cD2/cD3 (7/8 of output bytes) store fully
// coalesced per-lane; cD4/cD5/cA5 from lane subsets, contiguous bursts.
// Nontemporal stores (via clang ext_vector types — HIP float4 structs are
// rejected by the builtin) keep output from polluting L2/L3 so input stays
// L3-resident.

#define INV_SQRT2 0.70710678118654752440f

typedef float vfloat4 __attribute__((ext_vector_type(4)));
typedef float vfloat2 __attribute__((ext_vector_type(2)));

__global__ void __launch_bounds__(256)
haar5_kernel(const float* __restrict__ x, float* __restrict__ out) {
    const int i = threadIdx.x;                 // 0..255
    const long long blk = blockIdx.x;          // 0..16383
    const long long row = blk >> 2;            // 0..4095
    const int seg = (int)(blk & 3);            // quarter-row, 2048 elems

    const float* __restrict__ xr = x + row * 8192LL + (long long)seg * 2048;
    float* __restrict__ orow = out + row * 8192LL;

    // Load 8 consecutive floats: 2x vfloat4, lane-stride 32B.
    const vfloat4* __restrict__ src = reinterpret_cast<const vfloat4*>(xr) + i * 2;
    vfloat4 f0 = src[0];
    vfloat4 f1 = src[1];
    float v[8] = { f0.x, f0.y, f0.z, f0.w, f1.x, f1.y, f1.z, f1.w };

    // Level 1: 8 -> 4
    float d1[4], a1[4];
#pragma unroll
    for (int k = 0; k < 4; ++k) {
        d1[k] = (v[2 * k] - v[2 * k + 1]) * INV_SQRT2;
        a1[k] = (v[2 * k] + v[2 * k + 1]) * INV_SQRT2;
    }
    // Level 2: 4 -> 2
    float d2[2], a2[2];
#pragma unroll
    for (int k = 0; k < 2; ++k) {
        d2[k] = (a1[2 * k] - a1[2 * k + 1]) * INV_SQRT2;
        a2[k] = (a1[2 * k] + a1[2 * k + 1]) * INV_SQRT2;
    }
    // Level 3: 2 -> 1
    float d3 = (a2[0] - a2[1]) * INV_SQRT2;
    float a3 = (a2[0] + a2[1]) * INV_SQRT2;

    // Level 4: pair lanes (2k, 2k+1)
    float a3o = __shfl_xor(a3, 1, 64);
    float lo4 = (i & 1) ? a3o : a3;   // a3[2k]
    float hi4 = (i & 1) ? a3 : a3o;   // a3[2k+1]
    float d4 = (lo4 - hi4) * INV_SQRT2;
    float a4 = (lo4 + hi4) * INV_SQRT2;

    // Level 5: pair lane-groups
    float a4o = __shfl_xor(a4, 2, 64);
    float lo5 = (i & 2) ? a4o : a4;   // a4[2m]
    float hi5 = (i & 2) ? a4 : a4o;   // a4[2m+1]
    float d5 = (lo5 - hi5) * INV_SQRT2;
    float a5 = (lo5 + hi5) * INV_SQRT2;

    // Stores. Segment bases within the row:
    //   cA5: 0, cD5: 256, cD4: 512, cD3: 1024, cD2: 2048, cD1: 4096
    vfloat4 s1 = { d1[0], d1[1], d1[2], d1[3] };
    vfloat4* __restrict__ o1 = reinterpret_cast<vfloat4*>(orow + 4096 + seg * 1024) + i;
    __builtin_nontemporal_store(s1, o1);

    vfloat2 s2 = { d2[0], d2[1] };
    vfloat2* __restrict__ o2 = reinterpret_cast<vfloat2*>(orow + 2048 + seg * 512) + i;
    __builtin_nontemporal_store(s2, o2);

    __builtin_nontemporal_store(d3, orow + 1024 + seg * 256 + i);

    if ((i & 1) == 0)
        __builtin_nontemporal_store(d4, orow + 512 + seg * 128 + (i >> 1));

    if ((i & 3) == 0) {
        __builtin_nontemporal_store(d5, orow + 256 + seg * 64 + (i >> 2));
        __builtin_nontemporal_store(a5, orow + seg * 64 + (i >> 2));
    }
}

extern "C" void kernel_launch(void* const* d_in, const int* in_sizes, int n_in,
                              void* d_out, int out_size, void* d_ws, size_t ws_size,
                              hipStream_t stream) {
    const float* x = (const float*)d_in[0];
    float* out = (float*)d_out;
    // 4096 rows x 4 segment-blocks, 256 threads x 8 elems = 2048 elems/block.
    haar5_kernel<<<16384, 256, 0, stream>>>(x, out);
}